// Round 10
// baseline (7134.560 us; speedup 1.0000x reference)
//
#include <hip/hip_runtime.h>
#include <hip/hip_bf16.h>

#define Bsz  1024
#define Hsz  1024
#define Isz  69
#define Tn   74
#define KP   1152     // padded K = 1024 (h) + 128 (x)
#define XP   128      // bf16 x row pad (frames)
#define XPF  80       // fp32 x row pad (x0f, xG)
#define XLP  84       // fp32 x row pad in LDS

typedef short  short8 __attribute__((ext_vector_type(8)));
typedef float  f32x4  __attribute__((ext_vector_type(4)));
using ushort = unsigned short;

__device__ __forceinline__ ushort f2bf(float f) {
    unsigned u = __float_as_uint(f);
    return (ushort)((u + 0x7fffu + ((u >> 16) & 1u)) >> 16);  // RNE
}
__device__ __forceinline__ float bf2f(ushort u) {
    return __uint_as_float((unsigned)u << 16);
}

// async global -> LDS, 16B per lane, lane i lands at ldsbase + 16*i
__device__ __forceinline__ void gld_lds16(const void* g, void* l) {
    __builtin_amdgcn_global_load_lds(
        (const __attribute__((address_space(1))) unsigned int*)g,
        (__attribute__((address_space(3))) unsigned int*)l, 16, 0, 0);
}

__global__ void init_k(ushort* __restrict__ hbf, float* __restrict__ logit,
                       const float* __restrict__ fc2_b) {
    unsigned gid = blockIdx.x * 256 + threadIdx.x;
    if (gid < 1024u * 1024u) hbf[gid] = 0;
    if (gid < 1024u) logit[gid] = fc2_b[0];
}

// wpack[3072][1152] bf16 = [w_hh | w_ih | 0]; w1p[80][1024] bf16 (rows >=69 zero)
__global__ void pack_w(const float* __restrict__ w_ih, const float* __restrict__ w_hh,
                       const float* __restrict__ fc1_w,
                       ushort* __restrict__ wpack, ushort* __restrict__ w1p) {
    unsigned gid = blockIdx.x * 256 + threadIdx.x;
    const unsigned WN4 = 3072u * 288u;
    if (gid < WN4) {
        unsigned row = gid / 288u, c4 = (gid % 288u) * 4u;
        ushort4 o; ushort* po = (ushort*)&o;
#pragma unroll
        for (int e = 0; e < 4; ++e) {
            unsigned k = c4 + e; float v = 0.f;
            if (k < 1024u)       v = w_hh[(size_t)row * 1024u + k];
            else if (k < 1093u)  v = w_ih[(size_t)row * 69u + (k - 1024u)];
            po[e] = f2bf(v);
        }
        *(ushort4*)(wpack + (size_t)row * KP + c4) = o;
    } else if (gid < WN4 + 20480u) {
        unsigned g2 = gid - WN4;
        unsigned i = g2 / 256u, c4 = (g2 % 256u) * 4u;
        ushort4 o; ushort* po = (ushort*)&o;
#pragma unroll
        for (int e = 0; e < 4; ++e)
            po[e] = (i < 69u) ? f2bf(fc1_w[(size_t)i * 1024u + c4 + e]) : (ushort)0;
        *(ushort4*)(w1p + (size_t)i * 1024u + c4) = o;
    }
}

// frames_bf[74][1024][128] bf16 (zero-padded); x0f[1024][80] fp32 = frame0
__global__ void pack_f(const float* __restrict__ enc, const float* __restrict__ dec,
                       ushort* __restrict__ frames, float* __restrict__ x0f) {
    unsigned gid = blockIdx.x * 256 + threadIdx.x;
    const unsigned NF4 = 74u * 1024u * 32u;
    if (gid < NF4) {
        unsigned c4 = (gid & 31u) * 4u;
        unsigned b  = (gid >> 5) & 1023u;
        unsigned tf = gid >> 15;
        ushort4 o; ushort* po = (ushort*)&o;
#pragma unroll
        for (int e = 0; e < 4; ++e) {
            unsigned i = c4 + e; float v = 0.f;
            if (i < 69u)
                v = (tf < 50u) ? enc[((size_t)b * 50u + tf) * 69u + i]
                               : dec[((size_t)b * 24u + (tf - 50u)) * 69u + i];
            po[e] = f2bf(v);
        }
        *(ushort4*)(frames + (size_t)tf * 1024u * XP + (size_t)b * XP + c4) = o;
    } else if (gid < NF4 + 81920u) {
        unsigned g2 = gid - NF4;
        unsigned b = g2 / 80u, i = g2 % 80u;
        x0f[g2] = (i < 69u) ? enc[(size_t)b * 50u * 69u + i] : 0.f;
    }
}

// ---------------------------------------------------------------------------
// One GRU timestep per launch. Retiled for 2 blocks/CU: grid 512, block 256
// (4 waves). Block (bm 0..31, bn 0..15) = 32 m-rows x 64 n-cols (x3 gates).
// Each wave runs FULL K=1152 for its 16 cols -> complete accumulators, NO
// cross-wave reduction, zero epilogue syncs (2 syncthreads total). LDS
// 74.5KB (64KB staging + xLf) -> 2 blocks/CU for cross-block latency hiding.
// h carried bf16-only (r9-proven numerics). d>=1: fc1 fused (5 j-tiles on
// 4 waves; wave 0 takes tile 4), bn==0 exports x + accumulates logit.
// ---------------------------------------------------------------------------
__launch_bounds__(256, 2)
__global__ void gru_fused(
    const ushort* __restrict__ hbf,
    const ushort* __restrict__ xframe, const float* __restrict__ xprevG,
    const ushort* __restrict__ wpack, const ushort* __restrict__ w1p,
    const float* __restrict__ b_ih, const float* __restrict__ b_hh,
    const float* __restrict__ fc1_b, const float* __restrict__ fc2_w,
    ushort* __restrict__ hbf_out,
    float* __restrict__ xoutG, float* __restrict__ logitG, int d)
{
    __shared__ __align__(16) ushort ldsH[8 * 4096];   // 64KB: 8 stages x 32r x 128c
    __shared__ __align__(16) float  xLf[32 * XLP];    // 10.5KB fp32 x (block-local)

    const int t    = threadIdx.x;
    const int blk  = blockIdx.x;
    const int idx  = blk >> 3, xcd = blk & 7;
    const int bn   = xcd * 2 + (idx & 1);   // 0..15: XCD keeps 2 bn-slices L2-hot
    const int bm   = idx >> 1;              // 0..31: 32-row slab
    const int wave = t >> 6, lane = t & 63;
    const int quad = lane >> 4, l16 = lane & 15;
    const int p_   = lane & 15, rl_ = lane >> 4;

    // ---- stage ALL 8 h-stages (16 gld_lds issues/thread, one drain) ----
#pragma unroll
    for (int c = 0; c < 8; ++c) {
#pragma unroll
        for (int i2 = 0; i2 < 2; ++i2) {
            const int srow = wave * 8 + i2 * 4 + rl_;           // 0..31
            const int cc   = p_ ^ (srow & 15);                  // XOR swizzle (src side)
            const ushort* g = hbf + (size_t)(bm * 32 + srow) * 1024 + c * 128 + cc * 8;
            gld_lds16(g, &ldsH[c * 4096 + (wave * 8 + i2 * 4) * 128]);
        }
    }

    // ---- B frags init (L2-hot), distance-2 ring, full K per wave ----
    const ushort* bp0 = wpack + (size_t)(bn * 64 + wave * 16 + l16) * KP + quad * 8;
    const ushort* bp1 = bp0 + (size_t)1024 * KP;
    const ushort* bp2 = bp0 + (size_t)2048 * KP;
    short8 bq[2][3];
    bq[0][0] = *(const short8*)(bp0);      bq[0][1] = *(const short8*)(bp1);      bq[0][2] = *(const short8*)(bp2);
    bq[1][0] = *(const short8*)(bp0 + 32); bq[1][1] = *(const short8*)(bp1 + 32); bq[1][2] = *(const short8*)(bp2 + 32);

    // ---- x inputs (pre-sync: overlap with staging drain) ----
    short8 xf_[2][4];
    float  xp0[2][4], xp1[2][4];
    if (d < 1) {            // encode pass + decode step 0: x from frames
#pragma unroll
        for (int kk = 0; kk < 4; ++kk) {
            const int gg = kk * 4 + quad;
#pragma unroll
            for (int mt = 0; mt < 2; ++mt)
                xf_[mt][kk] = *(const short8*)(xframe + (size_t)(bm * 32 + mt * 16 + l16) * XP + gg * 8);
        }
    } else {                // fc1 residual x_{d-2}
        const int j = wave * 16 + l16;
#pragma unroll
        for (int fm = 0; fm < 2; ++fm)
#pragma unroll
            for (int r = 0; r < 4; ++r)
                xp0[fm][r] = xprevG[(size_t)(bm * 32 + fm * 16 + quad * 4 + r) * XPF + j];
        if (wave == 0) {
            const int j4 = 64 + l16;
#pragma unroll
            for (int fm = 0; fm < 2; ++fm)
#pragma unroll
                for (int r = 0; r < 4; ++r)
                    xp1[fm][r] = xprevG[(size_t)(bm * 32 + fm * 16 + quad * 4 + r) * XPF + j4];
        }
    }
    __syncthreads();        // h staged (single vmcnt drain)

    f32x4 accR[2], accZ[2], accNH[2], accNI[2];
#pragma unroll
    for (int i = 0; i < 2; ++i) {
        accR[i]  = (f32x4){0.f,0.f,0.f,0.f}; accZ[i]  = (f32x4){0.f,0.f,0.f,0.f};
        accNH[i] = (f32x4){0.f,0.f,0.f,0.f}; accNI[i] = (f32x4){0.f,0.f,0.f,0.f};
    }

#define MFMA_BF16 __builtin_amdgcn_mfma_f32_16x16x32_bf16
    // ---- h K-loop: 32 slots (8 stages x 4 kk), ring distance 2 (r8-proven) ----
#pragma unroll
    for (int q = 0; q < 32; ++q) {
        const int c  = q >> 2;
        const ushort* ab = &ldsH[c * 4096];
        const int g2 = (q & 3) * 4 + quad;
        const int pos = (g2 ^ l16) * 8;
        short8 a0 = *(const short8*)(ab + ( 0 + l16) * 128 + pos);
        short8 a1 = *(const short8*)(ab + (16 + l16) * 128 + pos);
        short8 b0 = bq[q & 1][0], b1v = bq[q & 1][1], b2v = bq[q & 1][2];
        {   // prefetch slot q+2 (stays within KP)
            bq[q & 1][0] = *(const short8*)(bp0 + (q + 2) * 32);
            bq[q & 1][1] = *(const short8*)(bp1 + (q + 2) * 32);
            bq[q & 1][2] = *(const short8*)(bp2 + (q + 2) * 32);
        }
        accR[0] = MFMA_BF16(a0, b0, accR[0],0,0,0);
        accZ[0] = MFMA_BF16(a0, b1v, accZ[0],0,0,0);
        accNH[0]= MFMA_BF16(a0, b2v, accNH[0],0,0,0);
        accR[1] = MFMA_BF16(a1, b0, accR[1],0,0,0);
        accZ[1] = MFMA_BF16(a1, b1v, accZ[1],0,0,0);
        accNH[1]= MFMA_BF16(a1, b2v, accNH[1],0,0,0);
    }

    // ---- fc1 (d>=1): x_{d-1} = xprev + h_{d-1}@w1p^T + b1; 5 j-tiles / 4 waves ----
    if (d >= 1) {
        auto fc1_tile = [&](int j, float (*xpv)[4]) {
            const ushort* bfp = w1p + (size_t)j * 1024 + quad * 8;
            f32x4 facc[2];
            facc[0] = (f32x4){0.f,0.f,0.f,0.f}; facc[1] = (f32x4){0.f,0.f,0.f,0.f};
#pragma unroll
            for (int c = 0; c < 8; ++c) {
#pragma unroll
                for (int q4 = 0; q4 < 4; ++q4) {
                    short8 bb = *(const short8*)(bfp + c * 128 + q4 * 32);
#pragma unroll
                    for (int fm = 0; fm < 2; ++fm) {
                        const int row = fm * 16 + l16;
                        short8 aa = *(const short8*)(&ldsH[c * 4096 + row * 128 + (((q4 * 4 + quad) ^ l16) * 8)]);
                        facc[fm] = MFMA_BF16(aa, bb, facc[fm],0,0,0);
                    }
                }
            }
            const float b1f = (j < Isz) ? fc1_b[j] : 0.f;
#pragma unroll
            for (int fm = 0; fm < 2; ++fm)
#pragma unroll
                for (int r = 0; r < 4; ++r) {
                    const int m = fm * 16 + quad * 4 + r;
                    xLf[m * XLP + j] = (j < Isz) ? (xpv[fm][r] + facc[fm][r] + b1f) : 0.f;
                }
        };
        fc1_tile(wave * 16 + l16, xp0);
        if (wave == 0) fc1_tile(64 + l16, xp1);
    }
    __syncthreads();    // sync1: xLf ready; all ldsH reads complete

    // ---- export x_{d-1} (bn==0 only) ----
    if (d >= 1 && bn == 0) {
        for (int i = t; i < 32 * XPF; i += 256) {
            const int r = i / XPF, c2 = i % XPF;
            xoutG[(size_t)(bm * 32 + r) * XPF + c2] = xLf[r * XLP + c2];
        }
    }

    // ---- x frags (d>=1: from xLf fp32 -> bf16) ----
    if (d >= 1) {
#pragma unroll
        for (int kk = 0; kk < 4; ++kk) {
            const int gg = kk * 4 + quad;
#pragma unroll
            for (int mt = 0; mt < 2; ++mt) {
                short8 a = (short8){0,0,0,0,0,0,0,0};
                if (gg < 10) {
                    const float* p = &xLf[(mt * 16 + l16) * XLP + gg * 8];
                    f32x4 v0 = *(const f32x4*)p;
                    f32x4 v1 = *(const f32x4*)(p + 4);
                    union { short8 s; ushort u[8]; } uu;
                    uu.u[0] = f2bf(v0[0]); uu.u[1] = f2bf(v0[1]);
                    uu.u[2] = f2bf(v0[2]); uu.u[3] = f2bf(v0[3]);
                    uu.u[4] = f2bf(v1[0]); uu.u[5] = f2bf(v1[1]);
                    uu.u[6] = f2bf(v1[2]); uu.u[7] = f2bf(v1[3]);
                    a = uu.s;
                }
                xf_[mt][kk] = a;
            }
        }
    }
    // ---- x MFMAs: slots 32..35; ring parity continues ----
#pragma unroll
    for (int kk = 0; kk < 4; ++kk) {
        short8 b0 = bq[kk & 1][0], b1v = bq[kk & 1][1], b2v = bq[kk & 1][2];
        if (kk < 2) {   // prefetch slots 34,35 (within KP)
            bq[kk & 1][0] = *(const short8*)(bp0 + (34 + kk) * 32);
            bq[kk & 1][1] = *(const short8*)(bp1 + (34 + kk) * 32);
            bq[kk & 1][2] = *(const short8*)(bp2 + (34 + kk) * 32);
        }
        accR[0] = MFMA_BF16(xf_[0][kk], b0, accR[0],0,0,0);
        accZ[0] = MFMA_BF16(xf_[0][kk], b1v, accZ[0],0,0,0);
        accNI[0]= MFMA_BF16(xf_[0][kk], b2v, accNI[0],0,0,0);
        accR[1] = MFMA_BF16(xf_[1][kk], b0, accR[1],0,0,0);
        accZ[1] = MFMA_BF16(xf_[1][kk], b1v, accZ[1],0,0,0);
        accNI[1]= MFMA_BF16(xf_[1][kk], b2v, accNI[1],0,0,0);
    }

    // ---- logit(d-1): bn==0, wave 3, single writer per row ----
    if (d >= 1 && bn == 0 && wave == 3 && lane < 32) {
        float lp = 0.f;
        for (int c2 = 0; c2 < Isz; ++c2)
            lp += fc2_w[(size_t)(d - 1) * Isz + c2] * xLf[lane * XLP + c2];
        logitG[bm * 32 + lane] += lp;
    }

    // ---- epilogue: accumulators complete per wave -> direct, no syncs ----
    {
        const int jcol = bn * 64 + wave * 16 + l16;
        const float bir = b_ih[jcol],        bhr = b_hh[jcol];
        const float biz = b_ih[1024 + jcol], bhz = b_hh[1024 + jcol];
        const float bin_= b_ih[2048 + jcol], bhn = b_hh[2048 + jcol];
        float hp[2][4];
#pragma unroll
        for (int mt = 0; mt < 2; ++mt)
#pragma unroll
            for (int r = 0; r < 4; ++r)
                hp[mt][r] = bf2f(hbf[(size_t)(bm * 32 + mt * 16 + quad * 4 + r) * 1024 + jcol]);
#pragma unroll
        for (int mt = 0; mt < 2; ++mt) {
#pragma unroll
            for (int r = 0; r < 4; ++r) {
                const int m = bm * 32 + mt * 16 + quad * 4 + r;
                float gr = accR[mt][r] + bir + bhr;
                float gz = accZ[mt][r] + biz + bhz;
                float rg = 1.f / (1.f + __expf(-gr));
                float zg = 1.f / (1.f + __expf(-gz));
                float nx = accNI[mt][r] + bin_ + rg * (accNH[mt][r] + bhn);
                nx = fminf(30.f, fmaxf(-30.f, nx));
                float e  = __expf(-2.f * nx);
                float ng = (1.f - e) / (1.f + e);
                float hn = (1.f - zg) * ng + zg * hp[mt][r];
                hbf_out[(size_t)m * 1024 + jcol] = f2bf(hn);
            }
        }
    }
#undef MFMA_BF16
}

// Tail: x_73 = x_72 + h_73@w1p^T + b1, logit(73), sigmoid. Grid 16 (bm of 64).
__launch_bounds__(512)
__global__ void tail_k(const ushort* __restrict__ hbf, const float* __restrict__ xprevG,
                       const ushort* __restrict__ w1p, const float* __restrict__ fc1_b,
                       const float* __restrict__ fc2_w, const float* __restrict__ logitG,
                       float* __restrict__ outp)
{
    __shared__ __align__(16) ushort ldsH[8 * 8192];
    __shared__ __align__(16) float  xLf[64 * XLP];
    const int t    = threadIdx.x;
    const int bm   = blockIdx.x;
    const int wave = t >> 6, lane = t & 63;
    const int quad = lane >> 4, l16 = lane & 15;
    const int p_   = lane & 15, rl_ = lane >> 4;

#pragma unroll
    for (int c = 0; c < 8; ++c) {
#pragma unroll
        for (int i2 = 0; i2 < 2; ++i2) {
            const int srow = wave * 8 + i2 * 4 + rl_;
            const int cc   = p_ ^ (srow & 15);
            const ushort* g = hbf + (size_t)(bm * 64 + srow) * 1024 + c * 128 + cc * 8;
            gld_lds16(g, &ldsH[c * 8192 + (wave * 8 + i2 * 4) * 128]);
        }
    }
    float xp[4][4];
    if (wave < 5) {
        const int j = wave * 16 + l16;
#pragma unroll
        for (int fm = 0; fm < 4; ++fm)
#pragma unroll
            for (int r = 0; r < 4; ++r)
                xp[fm][r] = xprevG[(size_t)(bm * 64 + fm * 16 + quad * 4 + r) * XPF + j];
    }
    __syncthreads();
    if (wave < 5) {
        const int j = wave * 16 + l16;
        const ushort* bfp = w1p + (size_t)j * 1024 + quad * 8;
        f32x4 facc[4];
#pragma unroll
        for (int i = 0; i < 4; ++i) facc[i] = (f32x4){0.f,0.f,0.f,0.f};
#pragma unroll
        for (int c = 0; c < 8; ++c) {
#pragma unroll
            for (int q4 = 0; q4 < 4; ++q4) {
                short8 bb = *(const short8*)(bfp + c * 128 + q4 * 32);
#pragma unroll
                for (int fm = 0; fm < 4; ++fm) {
                    const int row = fm * 16 + l16;
                    short8 aa = *(const short8*)(&ldsH[c * 8192 + row * 128 + (((q4 * 4 + quad) ^ l16) * 8)]);
                    facc[fm] = __builtin_amdgcn_mfma_f32_16x16x32_bf16(aa, bb, facc[fm],0,0,0);
                }
            }
        }
        const float b1f = (j < Isz) ? fc1_b[j] : 0.f;
#pragma unroll
        for (int fm = 0; fm < 4; ++fm)
#pragma unroll
            for (int r = 0; r < 4; ++r) {
                const int m = fm * 16 + quad * 4 + r;
                xLf[m * XLP + j] = (j < Isz) ? (xp[fm][r] + facc[fm][r] + b1f) : 0.f;
            }
    }
    __syncthreads();
    if (t < 64) {
        float lp = 0.f;
        for (int c2 = 0; c2 < Isz; ++c2)
            lp += fc2_w[(size_t)73 * Isz + c2] * xLf[t * XLP + c2];
        outp[bm * 64 + t] = 1.f / (1.f + __expf(-(logitG[bm * 64 + t] + lp)));
    }
}

extern "C" void kernel_launch(void* const* d_in, const int* in_sizes, int n_in,
                              void* d_out, int out_size, void* d_ws, size_t ws_size,
                              hipStream_t stream)
{
    const float* enc   = (const float*)d_in[0];
    const float* dec   = (const float*)d_in[1];
    const float* w_ih  = (const float*)d_in[2];
    const float* w_hh  = (const float*)d_in[3];
    const float* b_ih  = (const float*)d_in[4];
    const float* b_hh  = (const float*)d_in[5];
    const float* fc1_w = (const float*)d_in[6];
    const float* fc1_b = (const float*)d_in[7];
    const float* fc2_w = (const float*)d_in[8];
    const float* fc2_b = (const float*)d_in[9];
    float* out = (float*)d_out;

    char* ws = (char*)d_ws;
    size_t off = 0;
    auto alloc = [&](size_t bytes) -> void* {
        void* p = ws + off; off += (bytes + 255) & ~(size_t)255; return p;
    };
    ushort* wpack  = (ushort*)alloc((size_t)3072 * KP * 2);
    ushort* w1p    = (ushort*)alloc((size_t)80 * 1024 * 2);
    ushort* frames = (ushort*)alloc((size_t)Tn * 1024 * XP * 2);
    float*  x0f    = (float*) alloc((size_t)1024 * XPF * 4);
    ushort* hbfA   = (ushort*)alloc((size_t)1024 * 1024 * 2);
    ushort* hbfB   = (ushort*)alloc((size_t)1024 * 1024 * 2);
    float*  xGA    = (float*) alloc((size_t)1024 * XPF * 4);
    float*  xGB    = (float*) alloc((size_t)1024 * XPF * 4);
    float*  logit  = (float*) alloc((size_t)1024 * 4);

    init_k<<<4096, 256, 0, stream>>>(hbfA, logit, fc2_b);
    pack_w<<<3536, 256, 0, stream>>>(w_ih, w_hh, fc1_w, wpack, w1p);
    pack_f<<<9792, 256, 0, stream>>>(enc, dec, frames, x0f);

    ushort* hb_c = hbfA; ushort* hb_n = hbfB;

    // Encoding pass (74 steps) + decode step 0 (frame-0 input): d = 0
    for (int tt = 0; tt < Tn + 1; ++tt) {
        const ushort* xfr = frames + (size_t)(tt < Tn ? tt : 0) * 1024 * XP;
        gru_fused<<<512, 256, 0, stream>>>(hb_c, xfr, x0f, wpack, w1p,
                                           b_ih, b_hh, fc1_b, fc2_w,
                                           hb_n, xGA, logit, 0);
        { ushort* tb = hb_c; hb_c = hb_n; hb_n = tb; }
    }
    // Decode steps d = 1..73 (fc1 fused; x ping-pong: odd->xGA, even->xGB)
    for (int d = 1; d < Tn; ++d) {
        const float* xin  = (d == 1) ? x0f : ((d & 1) ? xGB : xGA);
        float*       xout = (d & 1) ? xGA : xGB;
        gru_fused<<<512, 256, 0, stream>>>(hb_c, frames, xin, wpack, w1p,
                                           b_ih, b_hh, fc1_b, fc2_w,
                                           hb_n, xout, logit, d);
        { ushort* tb = hb_c; hb_c = hb_n; hb_n = tb; }
    }
    // Tail: x_73 + logit(73) + sigmoid (d=73 wrote xGA)
    tail_k<<<16, 512, 0, stream>>>(hb_c, xGA, w1p, fc1_b, fc2_w, logit, out);
}

// Round 11
// 3600.419 us; speedup vs baseline: 1.9816x; 1.9816x over previous
//
#include <hip/hip_runtime.h>
#include <hip/hip_bf16.h>

#define Bsz  1024
#define Hsz  1024
#define Isz  69
#define Tn   74
#define KP   1152     // padded K = 1024 (h) + 128 (x)
#define XP   128      // bf16 x row pad (frames)
#define XPF  80       // fp32 x row pad (x0f, xG)
#define XLP  84       // fp32 x row pad in LDS

typedef short  short8 __attribute__((ext_vector_type(8)));
typedef float  f32x4  __attribute__((ext_vector_type(4)));
using ushort = unsigned short;

__device__ __forceinline__ ushort f2bf(float f) {
    unsigned u = __float_as_uint(f);
    return (ushort)((u + 0x7fffu + ((u >> 16) & 1u)) >> 16);  // RNE
}
__device__ __forceinline__ float bf2f(ushort u) {
    return __uint_as_float((unsigned)u << 16);
}

// async global -> LDS, 16B per lane, lane i lands at ldsbase + 16*i
__device__ __forceinline__ void gld_lds16(const void* g, void* l) {
    __builtin_amdgcn_global_load_lds(
        (const __attribute__((address_space(1))) unsigned int*)g,
        (__attribute__((address_space(3))) unsigned int*)l, 16, 0, 0);
}

__global__ void init_k(ushort* __restrict__ hbf, float* __restrict__ logit,
                       const float* __restrict__ fc2_b) {
    unsigned gid = blockIdx.x * 256 + threadIdx.x;
    if (gid < 1024u * 1024u) hbf[gid] = 0;
    if (gid < 1024u) logit[gid] = fc2_b[0];
}

// wpack[3072][1152] bf16 = [w_hh | w_ih | 0]; w1p[80][1024] bf16 (rows >=69 zero)
__global__ void pack_w(const float* __restrict__ w_ih, const float* __restrict__ w_hh,
                       const float* __restrict__ fc1_w,
                       ushort* __restrict__ wpack, ushort* __restrict__ w1p) {
    unsigned gid = blockIdx.x * 256 + threadIdx.x;
    const unsigned WN4 = 3072u * 288u;
    if (gid < WN4) {
        unsigned row = gid / 288u, c4 = (gid % 288u) * 4u;
        ushort4 o; ushort* po = (ushort*)&o;
#pragma unroll
        for (int e = 0; e < 4; ++e) {
            unsigned k = c4 + e; float v = 0.f;
            if (k < 1024u)       v = w_hh[(size_t)row * 1024u + k];
            else if (k < 1093u)  v = w_ih[(size_t)row * 69u + (k - 1024u)];
            po[e] = f2bf(v);
        }
        *(ushort4*)(wpack + (size_t)row * KP + c4) = o;
    } else if (gid < WN4 + 20480u) {
        unsigned g2 = gid - WN4;
        unsigned i = g2 / 256u, c4 = (g2 % 256u) * 4u;
        ushort4 o; ushort* po = (ushort*)&o;
#pragma unroll
        for (int e = 0; e < 4; ++e)
            po[e] = (i < 69u) ? f2bf(fc1_w[(size_t)i * 1024u + c4 + e]) : (ushort)0;
        *(ushort4*)(w1p + (size_t)i * 1024u + c4) = o;
    }
}

// frames_bf[74][1024][128] bf16 (zero-padded); x0f[1024][80] fp32 = frame0
__global__ void pack_f(const float* __restrict__ enc, const float* __restrict__ dec,
                       ushort* __restrict__ frames, float* __restrict__ x0f) {
    unsigned gid = blockIdx.x * 256 + threadIdx.x;
    const unsigned NF4 = 74u * 1024u * 32u;
    if (gid < NF4) {
        unsigned c4 = (gid & 31u) * 4u;
        unsigned b  = (gid >> 5) & 1023u;
        unsigned tf = gid >> 15;
        ushort4 o; ushort* po = (ushort*)&o;
#pragma unroll
        for (int e = 0; e < 4; ++e) {
            unsigned i = c4 + e; float v = 0.f;
            if (i < 69u)
                v = (tf < 50u) ? enc[((size_t)b * 50u + tf) * 69u + i]
                               : dec[((size_t)b * 24u + (tf - 50u)) * 69u + i];
            po[e] = f2bf(v);
        }
        *(ushort4*)(frames + (size_t)tf * 1024u * XP + (size_t)b * XP + c4) = o;
    } else if (gid < NF4 + 81920u) {
        unsigned g2 = gid - NF4;
        unsigned b = g2 / 80u, i = g2 % 80u;
        x0f[g2] = (i < 69u) ? enc[(size_t)b * 50u * 69u + i] : 0.f;
    }
}

// ---------------------------------------------------------------------------
// One GRU timestep per launch — r4 structure verbatim (best verified, 3688us)
// with ONE change: h carried bf16-only (no fp32 hf stream; h_prev widened
// from hbf in the epilogue). All 8 h-stages staged upfront via gld_lds (one
// drain). B-ring distance 2. 3-sync wk-reduction epilogue (r4-exact).
// d>=1: fc1 fused (waves 0-4); bn==0 exports x + accumulates logit.
// ---------------------------------------------------------------------------
__launch_bounds__(512, 2)
__global__ void gru_fused(
    const ushort* __restrict__ hbf,
    const ushort* __restrict__ xframe, const float* __restrict__ xprevG,
    const ushort* __restrict__ wpack, const ushort* __restrict__ w1p,
    const float* __restrict__ b_ih, const float* __restrict__ b_hh,
    const float* __restrict__ fc1_b, const float* __restrict__ fc2_w,
    ushort* __restrict__ hbf_out,
    float* __restrict__ xoutG, float* __restrict__ logitG, int d)
{
    __shared__ __align__(16) ushort ldsH[8 * 8192];   // 128KB: 8 stages x 64r x 128c
    __shared__ __align__(16) float  xLf[64 * XLP];    // 21KB fp32 x (block-local)

    const int t    = threadIdx.x;
    const int blk  = blockIdx.x;
    const int idx  = blk >> 3, xcd = blk & 7;
    const int bn   = xcd * 2 + (idx & 1);   // XCD keeps 2 bn-slices of wpack L2-hot
    const int bm   = idx >> 1;
    const int wave = t >> 6, lane = t & 63;
    const int wk   = wave >> 2, wn = wave & 3;
    const int quad = lane >> 4, l16 = lane & 15;
    const int p_   = lane & 15, rl_ = lane >> 4;

    // ---- stage ALL 8 h-stages (16 gld_lds issues/thread, one drain) ----
#pragma unroll
    for (int c = 0; c < 8; ++c) {
#pragma unroll
        for (int i2 = 0; i2 < 2; ++i2) {
            const int srow = wave * 8 + i2 * 4 + rl_;
            const int cc   = p_ ^ (srow & 15);          // XOR swizzle (src side)
            const ushort* g = hbf + (size_t)(bm * 64 + srow) * 1024 + c * 128 + cc * 8;
            gld_lds16(g, &ldsH[c * 8192 + (wave * 8 + i2 * 4) * 128]);
        }
    }

    // ---- B frags init (L2-hot), distance-2 ring (r4-proven) ----
    const ushort* bp0 = wpack + (size_t)(bn * 64 + wn * 16 + l16) * KP + quad * 8 + wk * 64;
    const ushort* bp1 = bp0 + (size_t)1024 * KP;
    const ushort* bp2 = bp0 + (size_t)2048 * KP;
    short8 bq[2][3];
    bq[0][0] = *(const short8*)(bp0);      bq[0][1] = *(const short8*)(bp1);      bq[0][2] = *(const short8*)(bp2);
    bq[1][0] = *(const short8*)(bp0 + 32); bq[1][1] = *(const short8*)(bp1 + 32); bq[1][2] = *(const short8*)(bp2 + 32);

    // ---- x inputs (pre-sync: overlap with staging drain) ----
    short8 xf_[4][2];
    float  xp[4][4];
    if (d < 1) {            // encode pass + decode step 0: x from frames
#pragma unroll
        for (int kk = 0; kk < 2; ++kk) {
            const int gg = (wk * 2 + kk) * 4 + quad;
#pragma unroll
            for (int mt = 0; mt < 4; ++mt)
                xf_[mt][kk] = *(const short8*)(xframe + (size_t)(bm * 64 + mt * 16 + l16) * XP + gg * 8);
        }
    } else if (wave < 5) {  // fc1 residual x_{d-2}
        const int j = wave * 16 + l16;
#pragma unroll
        for (int fm = 0; fm < 4; ++fm)
#pragma unroll
            for (int r = 0; r < 4; ++r)
                xp[fm][r] = xprevG[(size_t)(bm * 64 + fm * 16 + quad * 4 + r) * XPF + j];
    }
    __syncthreads();        // h staged (single vmcnt drain)

    f32x4 accR[4], accZ[4], accNH[4], accNI[4];
#pragma unroll
    for (int i = 0; i < 4; ++i) {
        accR[i]  = (f32x4){0.f,0.f,0.f,0.f}; accZ[i]  = (f32x4){0.f,0.f,0.f,0.f};
        accNH[i] = (f32x4){0.f,0.f,0.f,0.f}; accNI[i] = (f32x4){0.f,0.f,0.f,0.f};
    }

#define MFMA_BF16 __builtin_amdgcn_mfma_f32_16x16x32_bf16
    // ---- barrier-free h K-loop (r4 exact) ----
#pragma unroll
    for (int c = 0; c < 8; ++c) {
#pragma unroll
        for (int kk = 0; kk < 2; ++kk) {
            const int g   = (wk * 2 + kk) * 4 + quad;
            const ushort* ab = &ldsH[c * 8192];
            const int pos = (g ^ l16) * 8;
            short8 a0 = *(const short8*)(ab + ( 0 + l16) * 128 + pos);
            short8 a1 = *(const short8*)(ab + (16 + l16) * 128 + pos);
            short8 a2 = *(const short8*)(ab + (32 + l16) * 128 + pos);
            short8 a3 = *(const short8*)(ab + (48 + l16) * 128 + pos);
            short8 b0 = bq[kk][0], b1v = bq[kk][1], b2v = bq[kk][2];
            bq[kk][0] = *(const short8*)(bp0 + (c + 1) * 128 + kk * 32);
            bq[kk][1] = *(const short8*)(bp1 + (c + 1) * 128 + kk * 32);
            bq[kk][2] = *(const short8*)(bp2 + (c + 1) * 128 + kk * 32);
            accR[0] = MFMA_BF16(a0, b0, accR[0],0,0,0);
            accZ[0] = MFMA_BF16(a0, b1v, accZ[0],0,0,0);
            accNH[0]= MFMA_BF16(a0, b2v, accNH[0],0,0,0);
            accR[1] = MFMA_BF16(a1, b0, accR[1],0,0,0);
            accZ[1] = MFMA_BF16(a1, b1v, accZ[1],0,0,0);
            accNH[1]= MFMA_BF16(a1, b2v, accNH[1],0,0,0);
            accR[2] = MFMA_BF16(a2, b0, accR[2],0,0,0);
            accZ[2] = MFMA_BF16(a2, b1v, accZ[2],0,0,0);
            accNH[2]= MFMA_BF16(a2, b2v, accNH[2],0,0,0);
            accR[3] = MFMA_BF16(a3, b0, accR[3],0,0,0);
            accZ[3] = MFMA_BF16(a3, b1v, accZ[3],0,0,0);
            accNH[3]= MFMA_BF16(a3, b2v, accNH[3],0,0,0);
        }
    }

    // ---- fc1 (d>=1, waves 0..4): x_{d-1} = xprev + h_{d-1}@w1p^T + b1 ----
    if (d >= 1 && wave < 5) {
        const int j = wave * 16 + l16;                    // < 80
        const ushort* bfp = w1p + (size_t)j * 1024 + quad * 8;
        f32x4 facc[4];
#pragma unroll
        for (int i = 0; i < 4; ++i) facc[i] = (f32x4){0.f,0.f,0.f,0.f};
#pragma unroll
        for (int c = 0; c < 8; ++c) {
#pragma unroll
            for (int q4 = 0; q4 < 4; ++q4) {
                short8 bb = *(const short8*)(bfp + c * 128 + q4 * 32);
#pragma unroll
                for (int fm = 0; fm < 4; ++fm) {
                    const int row = fm * 16 + l16;
                    short8 aa = *(const short8*)(&ldsH[c * 8192 + row * 128 + (((q4 * 4 + quad) ^ l16) * 8)]);
                    facc[fm] = MFMA_BF16(aa, bb, facc[fm],0,0,0);
                }
            }
        }
        const float b1f = (j < Isz) ? fc1_b[j] : 0.f;
#pragma unroll
        for (int fm = 0; fm < 4; ++fm)
#pragma unroll
            for (int r = 0; r < 4; ++r) {
                const int m = fm * 16 + quad * 4 + r;
                xLf[m * XLP + j] = (j < Isz) ? (xp[fm][r] + facc[fm][r] + b1f) : 0.f;
            }
    }
    __syncthreads();                                      // xLf ready; ldsH reads done

    // ---- export x_{d-1} (bn==0 only; single writer per element) ----
    if (d >= 1 && bn == 0) {
        for (int i = t; i < 64 * XPF; i += 512) {
            const int r = i / XPF, c2 = i % XPF;
            xoutG[(size_t)(bm * 64 + r) * XPF + c2] = xLf[r * XLP + c2];
        }
    }

    // ---- c8 x frags (d>=1: from xLf fp32 -> bf16) ----
    if (d >= 1) {
#pragma unroll
        for (int kk = 0; kk < 2; ++kk) {
            const int gg = (wk * 2 + kk) * 4 + quad;
#pragma unroll
            for (int mt = 0; mt < 4; ++mt) {
                short8 a = (short8){0,0,0,0,0,0,0,0};
                if (gg < 10) {
                    const float* p = &xLf[(mt * 16 + l16) * XLP + gg * 8];
                    f32x4 v0 = *(const f32x4*)p;
                    f32x4 v1 = *(const f32x4*)(p + 4);
                    union { short8 s; ushort u[8]; } uu;
                    uu.u[0] = f2bf(v0[0]); uu.u[1] = f2bf(v0[1]);
                    uu.u[2] = f2bf(v0[2]); uu.u[3] = f2bf(v0[3]);
                    uu.u[4] = f2bf(v1[0]); uu.u[5] = f2bf(v1[1]);
                    uu.u[6] = f2bf(v1[2]); uu.u[7] = f2bf(v1[3]);
                    a = uu.s;
                }
                xf_[mt][kk] = a;
            }
        }
    }
    // ---- c8 MFMAs (x part) ----
#pragma unroll
    for (int kk = 0; kk < 2; ++kk) {
        short8 b0 = bq[kk][0], b1v = bq[kk][1], b2v = bq[kk][2];
        accR[0] = MFMA_BF16(xf_[0][kk], b0, accR[0],0,0,0);
        accZ[0] = MFMA_BF16(xf_[0][kk], b1v, accZ[0],0,0,0);
        accNI[0]= MFMA_BF16(xf_[0][kk], b2v, accNI[0],0,0,0);
        accR[1] = MFMA_BF16(xf_[1][kk], b0, accR[1],0,0,0);
        accZ[1] = MFMA_BF16(xf_[1][kk], b1v, accZ[1],0,0,0);
        accNI[1]= MFMA_BF16(xf_[1][kk], b2v, accNI[1],0,0,0);
        accR[2] = MFMA_BF16(xf_[2][kk], b0, accR[2],0,0,0);
        accZ[2] = MFMA_BF16(xf_[2][kk], b1v, accZ[2],0,0,0);
        accNI[2]= MFMA_BF16(xf_[2][kk], b2v, accNI[2],0,0,0);
        accR[3] = MFMA_BF16(xf_[3][kk], b0, accR[3],0,0,0);
        accZ[3] = MFMA_BF16(xf_[3][kk], b1v, accZ[3],0,0,0);
        accNI[3]= MFMA_BF16(xf_[3][kk], b2v, accNI[3],0,0,0);
    }

    // ---- cross-wk reduction via LDS (r4 exact) ----
    f32x4* red = (f32x4*)ldsH;                  // 2048 slots = 32 KB exactly
    const int rslot = wn * 64 + lane;
    if (wk == 1) {
#pragma unroll
        for (int mt = 0; mt < 4; ++mt) {
            red[mt * 256 + rslot]        = accR[mt];
            red[1024 + mt * 256 + rslot] = accZ[mt];
        }
    }
    __syncthreads();
    if (wk == 0) {
#pragma unroll
        for (int mt = 0; mt < 4; ++mt) {
            accR[mt] += red[mt * 256 + rslot];
            accZ[mt] += red[1024 + mt * 256 + rslot];
        }
    } else if (d >= 1 && bn == 0 && wave == 5) {
        // logit(d-1): single writer per row, plain RMW (cross-launch visible)
        const int row = lane;
        float lp = 0.f;
        for (int c2 = 0; c2 < Isz; ++c2)
            lp += fc2_w[(size_t)(d - 1) * Isz + c2] * xLf[row * XLP + c2];
        logitG[bm * 64 + row] += lp;
    }
    __syncthreads();
    if (wk == 1) {
#pragma unroll
        for (int mt = 0; mt < 4; ++mt) {
            red[mt * 256 + rslot]        = accNH[mt];
            red[1024 + mt * 256 + rslot] = accNI[mt];
        }
    }
    __syncthreads();
    if (wk == 0) {
#pragma unroll
        for (int mt = 0; mt < 4; ++mt) {
            accNH[mt] += red[mt * 256 + rslot];
            accNI[mt] += red[1024 + mt * 256 + rslot];
        }
        const int j = bn * 64 + wn * 16 + l16;
        const float bir = b_ih[j],        bhr = b_hh[j];
        const float biz = b_ih[1024 + j], bhz = b_hh[1024 + j];
        const float bin_= b_ih[2048 + j], bhn = b_hh[2048 + j];
#pragma unroll
        for (int mt = 0; mt < 4; ++mt) {
#pragma unroll
            for (int r = 0; r < 4; ++r) {
                int m = bm * 64 + mt * 16 + quad * 4 + r;
                float gr = accR[mt][r] + bir + bhr;
                float gz = accZ[mt][r] + biz + bhz;
                float rg = 1.f / (1.f + __expf(-gr));
                float zg = 1.f / (1.f + __expf(-gz));
                float nx = accNI[mt][r] + bin_ + rg * (accNH[mt][r] + bhn);
                nx = fminf(30.f, fmaxf(-30.f, nx));
                float e  = __expf(-2.f * nx);
                float ng = (1.f - e) / (1.f + e);
                float hp = bf2f(hbf[(size_t)m * 1024 + j]);   // bf16-only carry
                float hn = (1.f - zg) * ng + zg * hp;
                hbf_out[(size_t)m * 1024 + j] = f2bf(hn);
            }
        }
    }
#undef MFMA_BF16
}

// Tail: x_73 = x_72 + h_73@w1p^T + b1, logit(73), sigmoid. Grid 16 (bm).
__launch_bounds__(512)
__global__ void tail_k(const ushort* __restrict__ hbf, const float* __restrict__ xprevG,
                       const ushort* __restrict__ w1p, const float* __restrict__ fc1_b,
                       const float* __restrict__ fc2_w, const float* __restrict__ logitG,
                       float* __restrict__ outp)
{
    __shared__ __align__(16) ushort ldsH[8 * 8192];
    __shared__ __align__(16) float  xLf[64 * XLP];
    const int t    = threadIdx.x;
    const int bm   = blockIdx.x;
    const int wave = t >> 6, lane = t & 63;
    const int quad = lane >> 4, l16 = lane & 15;
    const int p_   = lane & 15, rl_ = lane >> 4;

#pragma unroll
    for (int c = 0; c < 8; ++c) {
#pragma unroll
        for (int i2 = 0; i2 < 2; ++i2) {
            const int srow = wave * 8 + i2 * 4 + rl_;
            const int cc   = p_ ^ (srow & 15);
            const ushort* g = hbf + (size_t)(bm * 64 + srow) * 1024 + c * 128 + cc * 8;
            gld_lds16(g, &ldsH[c * 8192 + (wave * 8 + i2 * 4) * 128]);
        }
    }
    float xp[4][4];
    if (wave < 5) {
        const int j = wave * 16 + l16;
#pragma unroll
        for (int fm = 0; fm < 4; ++fm)
#pragma unroll
            for (int r = 0; r < 4; ++r)
                xp[fm][r] = xprevG[(size_t)(bm * 64 + fm * 16 + quad * 4 + r) * XPF + j];
    }
    __syncthreads();
    if (wave < 5) {
        const int j = wave * 16 + l16;
        const ushort* bfp = w1p + (size_t)j * 1024 + quad * 8;
        f32x4 facc[4];
#pragma unroll
        for (int i = 0; i < 4; ++i) facc[i] = (f32x4){0.f,0.f,0.f,0.f};
#pragma unroll
        for (int c = 0; c < 8; ++c) {
#pragma unroll
            for (int q4 = 0; q4 < 4; ++q4) {
                short8 bb = *(const short8*)(bfp + c * 128 + q4 * 32);
#pragma unroll
                for (int fm = 0; fm < 4; ++fm) {
                    const int row = fm * 16 + l16;
                    short8 aa = *(const short8*)(&ldsH[c * 8192 + row * 128 + (((q4 * 4 + quad) ^ l16) * 8)]);
                    facc[fm] = __builtin_amdgcn_mfma_f32_16x16x32_bf16(aa, bb, facc[fm],0,0,0);
                }
            }
        }
        const float b1f = (j < Isz) ? fc1_b[j] : 0.f;
#pragma unroll
        for (int fm = 0; fm < 4; ++fm)
#pragma unroll
            for (int r = 0; r < 4; ++r) {
                const int m = fm * 16 + quad * 4 + r;
                xLf[m * XLP + j] = (j < Isz) ? (xp[fm][r] + facc[fm][r] + b1f) : 0.f;
            }
    }
    __syncthreads();
    if (t < 64) {
        float lp = 0.f;
        for (int c2 = 0; c2 < Isz; ++c2)
            lp += fc2_w[(size_t)73 * Isz + c2] * xLf[t * XLP + c2];
        outp[bm * 64 + t] = 1.f / (1.f + __expf(-(logitG[bm * 64 + t] + lp)));
    }
}

extern "C" void kernel_launch(void* const* d_in, const int* in_sizes, int n_in,
                              void* d_out, int out_size, void* d_ws, size_t ws_size,
                              hipStream_t stream)
{
    const float* enc   = (const float*)d_in[0];
    const float* dec   = (const float*)d_in[1];
    const float* w_ih  = (const float*)d_in[2];
    const float* w_hh  = (const float*)d_in[3];
    const float* b_ih  = (const float*)d_in[4];
    const float* b_hh  = (const float*)d_in[5];
    const float* fc1_w = (const float*)d_in[6];
    const float* fc1_b = (const float*)d_in[7];
    const float* fc2_w = (const float*)d_in[8];
    const float* fc2_b = (const float*)d_in[9];
    float* out = (float*)d_out;

    char* ws = (char*)d_ws;
    size_t off = 0;
    auto alloc = [&](size_t bytes) -> void* {
        void* p = ws + off; off += (bytes + 255) & ~(size_t)255; return p;
    };
    ushort* wpack  = (ushort*)alloc((size_t)3072 * KP * 2);
    ushort* w1p    = (ushort*)alloc((size_t)80 * 1024 * 2);
    ushort* frames = (ushort*)alloc((size_t)Tn * 1024 * XP * 2);
    float*  x0f    = (float*) alloc((size_t)1024 * XPF * 4);
    ushort* hbfA   = (ushort*)alloc((size_t)1024 * 1024 * 2);
    ushort* hbfB   = (ushort*)alloc((size_t)1024 * 1024 * 2);
    float*  xGA    = (float*) alloc((size_t)1024 * XPF * 4);
    float*  xGB    = (float*) alloc((size_t)1024 * XPF * 4);
    float*  logit  = (float*) alloc((size_t)1024 * 4);

    init_k<<<4096, 256, 0, stream>>>(hbfA, logit, fc2_b);
    pack_w<<<3536, 256, 0, stream>>>(w_ih, w_hh, fc1_w, wpack, w1p);
    pack_f<<<9792, 256, 0, stream>>>(enc, dec, frames, x0f);

    ushort* hb_c = hbfA; ushort* hb_n = hbfB;

    // Encoding pass (74 steps) + decode step 0 (frame-0 input): d = 0
    for (int tt = 0; tt < Tn + 1; ++tt) {
        const ushort* xfr = frames + (size_t)(tt < Tn ? tt : 0) * 1024 * XP;
        gru_fused<<<256, 512, 0, stream>>>(hb_c, xfr, x0f, wpack, w1p,
                                           b_ih, b_hh, fc1_b, fc2_w,
                                           hb_n, xGA, logit, 0);
        { ushort* tb = hb_c; hb_c = hb_n; hb_n = tb; }
    }
    // Decode steps d = 1..73 (fc1 fused; x ping-pong: odd->xGA, even->xGB)
    for (int d = 1; d < Tn; ++d) {
        const float* xin  = (d == 1) ? x0f : ((d & 1) ? xGB : xGA);
        float*       xout = (d & 1) ? xGA : xGB;
        gru_fused<<<256, 512, 0, stream>>>(hb_c, frames, xin, wpack, w1p,
                                           b_ih, b_hh, fc1_b, fc2_w,
                                           hb_n, xout, logit, d);
        { ushort* tb = hb_c; hb_c = hb_n; hb_n = tb; }
    }
    // Tail: x_73 + logit(73) + sigmoid (d=73 wrote xGA)
    tail_k<<<16, 512, 0, stream>>>(hb_c, xGA, w1p, fc1_b, fc2_w, logit, out);
}